// Round 1
// baseline (130.152 us; speedup 1.0000x reference)
//
#include <hip/hip_runtime.h>

#define LRELU_SLOPE 0.2f

// Fold attention vectors through W:  u[h][f] = sum_d W[h][f][d]*a_s[h][d],
// v[h][f] = sum_d W[h][f][d]*a_n[h][d].  Output layout: u[H*FIN] then v[H*FIN].
__global__ void uv_kernel(const float* __restrict__ W,
                          const float* __restrict__ a_s,
                          const float* __restrict__ a_n,
                          float* __restrict__ uv,
                          int FIN, int HF) {
    int g = blockIdx.x * 256 + threadIdx.x;
    if (g >= HF) return;
    int h = g / FIN;
    const float* wrow = W + (size_t)g * 128;   // W[h][f][*]  (g = h*FIN + f)
    const float* as = a_s + h * 128;
    const float* an = a_n + h * 128;
    float au = 0.f, av = 0.f;
    for (int d = 0; d < 128; ++d) {
        float w = wrow[d];
        au += w * as[d];
        av += w * an[d];
    }
    uv[g] = au;
    uv[HF + g] = av;
}

// One block per target m.  Stages K neighbor rows in LDS (computing e_neigh
// during the load), computes e_self from the self row, softmax over K, then
// writes the alpha-weighted neighbor feature y[m][h][f].
template<int FIN, int K>
__global__ __launch_bounds__(256)
void gat_attn_kernel(const float* __restrict__ x_self,
                     const float* __restrict__ x_neigh,   // [M*K, FIN]
                     const float* __restrict__ uv,        // u[2][FIN], v[2][FIN]
                     float* __restrict__ Y,               // [M, 2, FIN]
                     int M) {
    constexpr int F4 = FIN / 4;          // float4 lanes per row (32 or 64)
    constexpr int RPI = 256 / F4;        // rows loaded per iteration (8 or 4)
    __shared__ float xn[K * FIN];
    __shared__ float en_s[K][2];
    __shared__ float es_s[2];
    __shared__ float al_s[K][2];

    const int m = blockIdx.x;
    const int t = threadIdx.x;
    const int rlane = t % F4;
    const int rgrp  = t / F4;

    const float4 u0 = *(const float4*)(uv + 0 * FIN + 4 * rlane);
    const float4 u1 = *(const float4*)(uv + 1 * FIN + 4 * rlane);
    const float4 v0 = *(const float4*)(uv + 2 * FIN + 4 * rlane);
    const float4 v1 = *(const float4*)(uv + 3 * FIN + 4 * rlane);

    // rows 0..K-1: neighbors (dot with v);  row K: self row (dot with u)
    for (int r = rgrp; r <= K; r += RPI) {
        const float* src = (r < K) ? (x_neigh + ((size_t)m * K + r) * FIN)
                                   : (x_self + (size_t)m * FIN);
        float4 g = *(const float4*)(src + 4 * rlane);
        if (r < K) *(float4*)(&xn[r * FIN + 4 * rlane]) = g;
        float4 c0 = (r < K) ? v0 : u0;
        float4 c1 = (r < K) ? v1 : u1;
        float p0 = g.x * c0.x + g.y * c0.y + g.z * c0.z + g.w * c0.w;
        float p1 = g.x * c1.x + g.y * c1.y + g.z * c1.z + g.w * c1.w;
        #pragma unroll
        for (int off = F4 / 2; off > 0; off >>= 1) {
            p0 += __shfl_xor(p0, off);
            p1 += __shfl_xor(p1, off);
        }
        if (rlane == 0) {
            if (r < K) { en_s[r][0] = p0; en_s[r][1] = p1; }
            else       { es_s[0] = p0; es_s[1] = p1; }
        }
    }
    __syncthreads();

    // softmax over K for both heads, done by wave 0 (lanes 0..31: h=0, 32..63: h=1)
    if (t < 64) {
        int h = t >> 5, k = t & 31;
        float e = -1e30f;
        if (k < K) {
            float z = es_s[h] + en_s[k][h];
            e = (z >= 0.f) ? z : LRELU_SLOPE * z;
        }
        float mx = e;
        #pragma unroll
        for (int off = 16; off > 0; off >>= 1) mx = fmaxf(mx, __shfl_xor(mx, off));
        float ex = (k < K) ? expf(e - mx) : 0.f;
        float s = ex;
        #pragma unroll
        for (int off = 16; off > 0; off >>= 1) s += __shfl_xor(s, off);
        if (k < K) al_s[k][h] = ex / s;
    }
    __syncthreads();

    // y[h][f] = sum_k alpha[k][h] * xn[k][f]
    #pragma unroll
    for (int c = t; c < 2 * FIN; c += 256) {
        int h = c / FIN, f = c % FIN;
        float acc = 0.f;
        #pragma unroll
        for (int k = 0; k < K; ++k) acc += al_s[k][h] * xn[k * FIN + f];
        Y[((size_t)m * 2 + h) * FIN + f] = acc;
    }
}

// out[m][h*128+d] = sum_f Yin[m][h][f] * W[h][f][d].
// Tile: 32 rows x 128 cols per block, one head per blockIdx.y.
template<int FIN>
__global__ __launch_bounds__(256)
void proj_kernel(const float* __restrict__ Yin,  // [M][H][FIN]
                 const float* __restrict__ W,    // [H][FIN][128]
                 float* __restrict__ out,        // [M][H*128]
                 int M, int H) {
    constexpr int LDSROW = FIN + 1;              // +1 pad: kills stride-128 bank conflict
    __shared__ float ys[32 * LDSROW];
    const int h = blockIdx.y;
    const int m0 = blockIdx.x * 32;
    const int t = threadIdx.x;

    for (int i = t * 4; i < 32 * FIN; i += 1024) {
        int r = i / FIN, f = i % FIN;
        float4 g = *(const float4*)(Yin + ((size_t)(m0 + r) * H + h) * FIN + f);
        ys[r * LDSROW + f + 0] = g.x;
        ys[r * LDSROW + f + 1] = g.y;
        ys[r * LDSROW + f + 2] = g.z;
        ys[r * LDSROW + f + 3] = g.w;
    }
    __syncthreads();

    const int dg = t & 31;   // d0 = 4*dg
    const int rg = t >> 5;   // rows rg*4 .. rg*4+3
    float4 acc[4];
    #pragma unroll
    for (int j = 0; j < 4; ++j) acc[j] = make_float4(0.f, 0.f, 0.f, 0.f);

    const float* wp = W + (size_t)h * FIN * 128 + 4 * dg;
    #pragma unroll 4
    for (int f = 0; f < FIN; ++f) {
        float4 w4 = *(const float4*)(wp + (size_t)f * 128);
        #pragma unroll
        for (int j = 0; j < 4; ++j) {
            float x = ys[(rg * 4 + j) * LDSROW + f];
            acc[j].x += x * w4.x;
            acc[j].y += x * w4.y;
            acc[j].z += x * w4.z;
            acc[j].w += x * w4.w;
        }
    }
    #pragma unroll
    for (int j = 0; j < 4; ++j) {
        *(float4*)(out + ((size_t)(m0 + rg * 4 + j)) * (H * 128) + h * 128 + 4 * dg) = acc[j];
    }
}

extern "C" void kernel_launch(void* const* d_in, const int* in_sizes, int n_in,
                              void* d_out, int out_size, void* d_ws, size_t ws_size,
                              hipStream_t stream) {
    const float* h0  = (const float*)d_in[0];
    const float* h1  = (const float*)d_in[1];
    const float* h2  = (const float*)d_in[2];
    const float* W0  = (const float*)d_in[3];
    const float* as0 = (const float*)d_in[4];
    const float* an0 = (const float*)d_in[5];
    const float* W1  = (const float*)d_in[6];
    const float* as1 = (const float*)d_in[7];
    const float* an1 = (const float*)d_in[8];
    const float* fcW = (const float*)d_in[9];
    float* outp = (float*)d_out;

    float* ws  = (float*)d_ws;
    float* uv0 = ws;                            //  512 floats
    float* uv1 = uv0 + 512;                     // 1024 floats
    float* Y1  = uv1 + 1024;                    // 10240*256
    float* H1  = Y1  + (size_t)10240 * 256;     // 10240*256
    float* Y0  = H1  + (size_t)10240 * 256;     // 1024*256
    float* H0a = Y0  + (size_t)1024 * 256;      // 1024*256
    float* Y0b = H0a + (size_t)1024 * 256;      // 1024*512
    float* H0b = Y0b + (size_t)1024 * 512;      // 1024*256

    // layer 0 folded attention vectors
    hipLaunchKernelGGL(uv_kernel, dim3(1), dim3(256), 0, stream, W0, as0, an0, uv0, 128, 256);
    // layer 1 folded attention vectors (independent; queue early)
    hipLaunchKernelGGL(uv_kernel, dim3(2), dim3(256), 0, stream, W1, as1, an1, uv1, 256, 512);

    // layer 0, j=1:  self=h1, neigh=h2 (K=25)  -> H1 [10240,256]
    hipLaunchKernelGGL((gat_attn_kernel<128, 25>), dim3(10240), dim3(256), 0, stream,
                       h1, h2, uv0, Y1, 10240);
    hipLaunchKernelGGL((proj_kernel<128>), dim3(320, 2), dim3(256), 0, stream,
                       Y1, W0, H1, 10240, 2);

    // layer 0, j=0:  self=h0, neigh=h1 (K=10)  -> H0a [1024,256]
    hipLaunchKernelGGL((gat_attn_kernel<128, 10>), dim3(1024), dim3(256), 0, stream,
                       h0, h1, uv0, Y0, 1024);
    hipLaunchKernelGGL((proj_kernel<128>), dim3(32, 2), dim3(256), 0, stream,
                       Y0, W0, H0a, 1024, 2);

    // layer 1, j=0:  self=H0a, neigh=H1 (K=10, FIN=256)  -> H0b [1024,256]
    hipLaunchKernelGGL((gat_attn_kernel<256, 10>), dim3(1024), dim3(256), 0, stream,
                       H0a, H1, uv1, Y0b, 1024);
    hipLaunchKernelGGL((proj_kernel<256>), dim3(32, 2), dim3(256), 0, stream,
                       Y0b, W1, H0b, 1024, 2);

    // final fc:  out = H0b @ fc_W   (treated as H=1, FIN=256)
    hipLaunchKernelGGL((proj_kernel<256>), dim3(32, 1), dim3(256), 0, stream,
                       H0b, fcW, outp, 1024, 1);
}

// Round 2
// 83.171 us; speedup vs baseline: 1.5649x; 1.5649x over previous
//
#include <hip/hip_runtime.h>

#define LRELU_SLOPE 0.2f

// ---- uv_all: fold attention vectors through W for both layers, coalesced ----
// One wave per row. rows 0..255: layer0 (g=h*128+f); rows 256..767: layer1 (g=h*256+f).
// uv0 layout: u[2][128] @0, v[2][128] @256.  uv1: u[2][256] @0, v[2][256] @512.
__global__ __launch_bounds__(256)
void uv_all_kernel(const float* __restrict__ W0, const float* __restrict__ as0,
                   const float* __restrict__ an0,
                   const float* __restrict__ W1, const float* __restrict__ as1,
                   const float* __restrict__ an1,
                   float* __restrict__ uv0, float* __restrict__ uv1) {
    const int wid = blockIdx.x * 4 + (threadIdx.x >> 6);
    const int lane = threadIdx.x & 63;
    const float* wrow;
    const float* as;
    const float* an;
    if (wid < 256) {
        wrow = W0 + (size_t)wid * 128;
        int h = wid >> 7;
        as = as0 + h * 128; an = an0 + h * 128;
    } else {
        int g = wid - 256;
        wrow = W1 + (size_t)g * 128;
        int h = g >> 8;
        as = as1 + h * 128; an = an1 + h * 128;
    }
    float2 w = *(const float2*)(wrow + 2 * lane);
    float2 s = *(const float2*)(as + 2 * lane);
    float2 n = *(const float2*)(an + 2 * lane);
    float au = w.x * s.x + w.y * s.y;
    float av = w.x * n.x + w.y * n.y;
    #pragma unroll
    for (int off = 32; off > 0; off >>= 1) {
        au += __shfl_xor(au, off);
        av += __shfl_xor(av, off);
    }
    if (lane == 0) {
        if (wid < 256) { uv0[wid] = au; uv0[256 + wid] = av; }
        else { int g = wid - 256; uv1[g] = au; uv1[512 + g] = av; }
    }
}

// ---- big level: one block per target m (M=10240, K=25, FIN=128) -> Y1 ----
template<int FIN, int K>
__global__ __launch_bounds__(256)
void gat_attn_kernel(const float* __restrict__ x_self,
                     const float* __restrict__ x_neigh,   // [M*K, FIN]
                     const float* __restrict__ uv,        // u[2][FIN], v[2][FIN]
                     float* __restrict__ Y,               // [M, 2, FIN]
                     int M) {
    constexpr int F4 = FIN / 4;
    constexpr int RPI = 256 / F4;
    __shared__ float xn[K * FIN];
    __shared__ float en_s[K][2];
    __shared__ float es_s[2];
    __shared__ float al_s[K][2];

    const int m = blockIdx.x;
    const int t = threadIdx.x;
    const int rlane = t % F4;
    const int rgrp  = t / F4;

    const float4 u0 = *(const float4*)(uv + 0 * FIN + 4 * rlane);
    const float4 u1 = *(const float4*)(uv + 1 * FIN + 4 * rlane);
    const float4 v0 = *(const float4*)(uv + 2 * FIN + 4 * rlane);
    const float4 v1 = *(const float4*)(uv + 3 * FIN + 4 * rlane);

    for (int r = rgrp; r <= K; r += RPI) {
        const float* src = (r < K) ? (x_neigh + ((size_t)m * K + r) * FIN)
                                   : (x_self + (size_t)m * FIN);
        float4 g = *(const float4*)(src + 4 * rlane);
        if (r < K) *(float4*)(&xn[r * FIN + 4 * rlane]) = g;
        float4 c0 = (r < K) ? v0 : u0;
        float4 c1 = (r < K) ? v1 : u1;
        float p0 = g.x * c0.x + g.y * c0.y + g.z * c0.z + g.w * c0.w;
        float p1 = g.x * c1.x + g.y * c1.y + g.z * c1.z + g.w * c1.w;
        #pragma unroll
        for (int off = F4 / 2; off > 0; off >>= 1) {
            p0 += __shfl_xor(p0, off);
            p1 += __shfl_xor(p1, off);
        }
        if (rlane == 0) {
            if (r < K) { en_s[r][0] = p0; en_s[r][1] = p1; }
            else       { es_s[0] = p0; es_s[1] = p1; }
        }
    }
    __syncthreads();

    if (t < 64) {
        int h = t >> 5, k = t & 31;
        float e = -1e30f;
        if (k < K) {
            float z = es_s[h] + en_s[k][h];
            e = (z >= 0.f) ? z : LRELU_SLOPE * z;
        }
        float mx = e;
        #pragma unroll
        for (int off = 16; off > 0; off >>= 1) mx = fmaxf(mx, __shfl_xor(mx, off));
        float ex = (k < K) ? expf(e - mx) : 0.f;
        float s = ex;
        #pragma unroll
        for (int off = 16; off > 0; off >>= 1) s += __shfl_xor(s, off);
        if (k < K) al_s[k][h] = ex / s;
    }
    __syncthreads();

    for (int c = t; c < 2 * FIN; c += 256) {
        int h = c / FIN, f = c % FIN;
        float acc = 0.f;
        #pragma unroll
        for (int k = 0; k < K; ++k) acc += al_s[k][h] * xn[k * FIN + f];
        Y[((size_t)m * 2 + h) * FIN + f] = acc;
    }
}

// ---- mid: blocks 0..639 = proj(Y1 -> H1); blocks 640..1151 = fused attn+proj (h0,h1 -> H0a) ----
__global__ __launch_bounds__(256)
void mid_kernel(const float* __restrict__ Y1, const float* __restrict__ W0,
                float* __restrict__ H1,
                const float* __restrict__ h0, const float* __restrict__ h1,
                const float* __restrict__ uv0, float* __restrict__ H0a) {
    __shared__ float smem[4128];            // proj: 32 x 129 ; fused: xn 22x128 + y 512
    __shared__ float en[2][11][2];
    __shared__ float al[2][10][2];
    const int t = threadIdx.x;

    if (blockIdx.x < 640) {
        // proj: H1[m][h*128+d] = sum_f Y1[m][h][f] * W0[h][f][d]
        const int h = blockIdx.x / 320;
        const int m0 = (blockIdx.x % 320) * 32;
        for (int i = t * 4; i < 32 * 128; i += 1024) {
            int r = i >> 7, f = i & 127;
            float4 g = *(const float4*)(Y1 + ((size_t)(m0 + r) * 2 + h) * 128 + f);
            smem[r * 129 + f + 0] = g.x;
            smem[r * 129 + f + 1] = g.y;
            smem[r * 129 + f + 2] = g.z;
            smem[r * 129 + f + 3] = g.w;
        }
        __syncthreads();
        const int dg = t & 31;
        const int rg = t >> 5;
        float4 acc[4];
        #pragma unroll
        for (int j = 0; j < 4; ++j) acc[j] = make_float4(0.f, 0.f, 0.f, 0.f);
        const float* wp = W0 + (size_t)h * 128 * 128 + 4 * dg;
        #pragma unroll 4
        for (int f = 0; f < 128; ++f) {
            float4 w4 = *(const float4*)(wp + (size_t)f * 128);
            #pragma unroll
            for (int j = 0; j < 4; ++j) {
                float x = smem[(rg * 4 + j) * 129 + f];
                acc[j].x += x * w4.x;
                acc[j].y += x * w4.y;
                acc[j].z += x * w4.z;
                acc[j].w += x * w4.w;
            }
        }
        #pragma unroll
        for (int j = 0; j < 4; ++j)
            *(float4*)(H1 + (size_t)(m0 + rg * 4 + j) * 256 + h * 128 + 4 * dg) = acc[j];
    } else {
        // fused GAT(K=10, FIN=128) + projection; 2 targets per block
        const int m0 = (blockIdx.x - 640) * 2;
        const int rlane = t & 31;
        const int rg = t >> 5;                // 8 row groups
        const float4 u0 = *(const float4*)(uv0 + 0 + 4 * rlane);
        const float4 u1 = *(const float4*)(uv0 + 128 + 4 * rlane);
        const float4 v0 = *(const float4*)(uv0 + 256 + 4 * rlane);
        const float4 v1 = *(const float4*)(uv0 + 384 + 4 * rlane);
        for (int rho = rg; rho < 22; rho += 8) {
            int r = rho / 11, k = rho % 11;
            int m = m0 + r;
            const float* src = (k < 10) ? (h1 + ((size_t)m * 10 + k) * 128)
                                        : (h0 + (size_t)m * 128);
            float4 g = *(const float4*)(src + 4 * rlane);
            *(float4*)(&smem[rho * 128 + 4 * rlane]) = g;
            float4 c0 = (k < 10) ? v0 : u0;
            float4 c1 = (k < 10) ? v1 : u1;
            float p0 = g.x * c0.x + g.y * c0.y + g.z * c0.z + g.w * c0.w;
            float p1 = g.x * c1.x + g.y * c1.y + g.z * c1.z + g.w * c1.w;
            #pragma unroll
            for (int off = 16; off > 0; off >>= 1) {
                p0 += __shfl_xor(p0, off);
                p1 += __shfl_xor(p1, off);
            }
            if (rlane == 0) { en[r][k][0] = p0; en[r][k][1] = p1; }
        }
        __syncthreads();
        if (t < 128) {
            int r = t >> 6, h = (t >> 5) & 1, k = t & 31;
            float e = -1e30f;
            if (k < 10) {
                float z = en[r][10][h] + en[r][k][h];
                e = (z >= 0.f) ? z : LRELU_SLOPE * z;
            }
            float mx = e;
            #pragma unroll
            for (int off = 16; off > 0; off >>= 1) mx = fmaxf(mx, __shfl_xor(mx, off));
            float ex = (k < 10) ? expf(e - mx) : 0.f;
            float s = ex;
            #pragma unroll
            for (int off = 16; off > 0; off >>= 1) s += __shfl_xor(s, off);
            if (k < 10) al[r][k][h] = ex / s;
        }
        __syncthreads();
        // y[r][h][f] -> smem[2816 + r*256 + h*128 + f]  (== 2816 + c)
        #pragma unroll
        for (int i = 0; i < 2; ++i) {
            int c = t + 256 * i;
            int r = c >> 8, rem = c & 255, h = rem >> 7, f = rem & 127;
            float acc = 0.f;
            #pragma unroll
            for (int k = 0; k < 10; ++k) acc += al[r][k][h] * smem[(r * 11 + k) * 128 + f];
            smem[2816 + c] = acc;
        }
        __syncthreads();
        // proj: H0a[m][h*128+d] = sum_f y[r][h][f] * W0[h][f][d];  t = h*128+d
        const int h = t >> 7, d = t & 127;
        float acc0 = 0.f, acc1 = 0.f;
        const float* wp = W0 + (size_t)h * 128 * 128 + d;
        #pragma unroll 8
        for (int f = 0; f < 128; ++f) {
            float w = wp[(size_t)f * 128];
            acc0 += smem[2816 + h * 128 + f] * w;
            acc1 += smem[2816 + 256 + h * 128 + f] * w;
        }
        H0a[(size_t)(m0 + 0) * 256 + t] = acc0;
        H0a[(size_t)(m0 + 1) * 256 + t] = acc1;
    }
}

// ---- tail2: fused GAT(K=10, FIN=256) + proj(W1) + FC -> out; 2 targets/block ----
__global__ __launch_bounds__(256)
void tail2_kernel(const float* __restrict__ H0a, const float* __restrict__ H1,
                  const float* __restrict__ uv1, const float* __restrict__ W1,
                  const float* __restrict__ fcW, float* __restrict__ out) {
    __shared__ float smem[7168];   // xn 22x256 (5632) + y 1024 (@5632) + h0b 512 (@6656)
    __shared__ float en[2][11][2];
    __shared__ float al[2][10][2];
    const int t = threadIdx.x;
    const int m0 = blockIdx.x * 2;
    const int rlane = t & 63;
    const int rg = t >> 6;                    // 4 row groups
    const float4 u0 = *(const float4*)(uv1 + 0 + 4 * rlane);
    const float4 u1 = *(const float4*)(uv1 + 256 + 4 * rlane);
    const float4 v0 = *(const float4*)(uv1 + 512 + 4 * rlane);
    const float4 v1 = *(const float4*)(uv1 + 768 + 4 * rlane);
    for (int rho = rg; rho < 22; rho += 4) {
        int r = rho / 11, k = rho % 11;
        int m = m0 + r;
        const float* src = (k < 10) ? (H1 + ((size_t)m * 10 + k) * 256)
                                    : (H0a + (size_t)m * 256);
        float4 g = *(const float4*)(src + 4 * rlane);
        *(float4*)(&smem[rho * 256 + 4 * rlane]) = g;
        float4 c0 = (k < 10) ? v0 : u0;
        float4 c1 = (k < 10) ? v1 : u1;
        float p0 = g.x * c0.x + g.y * c0.y + g.z * c0.z + g.w * c0.w;
        float p1 = g.x * c1.x + g.y * c1.y + g.z * c1.z + g.w * c1.w;
        #pragma unroll
        for (int off = 32; off > 0; off >>= 1) {
            p0 += __shfl_xor(p0, off);
            p1 += __shfl_xor(p1, off);
        }
        if (rlane == 0) { en[r][k][0] = p0; en[r][k][1] = p1; }
    }
    __syncthreads();
    if (t < 128) {
        int r = t >> 6, h = (t >> 5) & 1, k = t & 31;
        float e = -1e30f;
        if (k < 10) {
            float z = en[r][10][h] + en[r][k][h];
            e = (z >= 0.f) ? z : LRELU_SLOPE * z;
        }
        float mx = e;
        #pragma unroll
        for (int off = 16; off > 0; off >>= 1) mx = fmaxf(mx, __shfl_xor(mx, off));
        float ex = (k < 10) ? expf(e - mx) : 0.f;
        float s = ex;
        #pragma unroll
        for (int off = 16; off > 0; off >>= 1) s += __shfl_xor(s, off);
        if (k < 10) al[r][k][h] = ex / s;
    }
    __syncthreads();
    // y[r][h][f] -> smem[5632 + r*512 + h*256 + f]  (== 5632 + c)
    #pragma unroll
    for (int i = 0; i < 4; ++i) {
        int c = t + 256 * i;
        int r = c >> 9, rem = c & 511, h = rem >> 8, f = rem & 255;
        float acc = 0.f;
        #pragma unroll
        for (int k = 0; k < 10; ++k) acc += al[r][k][h] * smem[(r * 11 + k) * 256 + f];
        smem[5632 + c] = acc;
    }
    __syncthreads();
    // h0b[r][h*128+d] = sum_f y[r][h][f] * W1[h][f][d];  t = h*128+d
    {
        const int h = t >> 7;
        const int d = t & 127;
        float acc0 = 0.f, acc1 = 0.f;
        const float* wp = W1 + (size_t)h * 256 * 128 + d;
        #pragma unroll 8
        for (int f = 0; f < 256; ++f) {
            float w = wp[(size_t)f * 128];
            acc0 += smem[5632 + h * 256 + f] * w;
            acc1 += smem[5632 + 512 + h * 256 + f] * w;
        }
        smem[6656 + t] = acc0;
        smem[6656 + 256 + t] = acc1;
    }
    __syncthreads();
    // out[m][o] = sum_f h0b[r][f] * fcW[f][o];  t = r*128+o
    {
        const int r = t >> 7;
        const int o = t & 127;
        float acc = 0.f;
        #pragma unroll 8
        for (int f = 0; f < 256; ++f)
            acc += smem[6656 + r * 256 + f] * fcW[(size_t)f * 128 + o];
        out[(size_t)(m0 + r) * 128 + o] = acc;
    }
}

extern "C" void kernel_launch(void* const* d_in, const int* in_sizes, int n_in,
                              void* d_out, int out_size, void* d_ws, size_t ws_size,
                              hipStream_t stream) {
    const float* h0  = (const float*)d_in[0];
    const float* h1  = (const float*)d_in[1];
    const float* h2  = (const float*)d_in[2];
    const float* W0  = (const float*)d_in[3];
    const float* as0 = (const float*)d_in[4];
    const float* an0 = (const float*)d_in[5];
    const float* W1  = (const float*)d_in[6];
    const float* as1 = (const float*)d_in[7];
    const float* an1 = (const float*)d_in[8];
    const float* fcW = (const float*)d_in[9];
    float* outp = (float*)d_out;

    float* ws  = (float*)d_ws;
    float* uv0 = ws;                            //  512 floats
    float* uv1 = uv0 + 512;                     // 1024 floats
    float* Y1  = uv1 + 1024;                    // 10240*256
    float* H1  = Y1  + (size_t)10240 * 256;     // 10240*256
    float* H0a = H1  + (size_t)10240 * 256;     // 1024*256

    hipLaunchKernelGGL(uv_all_kernel, dim3(192), dim3(256), 0, stream,
                       W0, as0, an0, W1, as1, an1, uv0, uv1);

    hipLaunchKernelGGL((gat_attn_kernel<128, 25>), dim3(10240), dim3(256), 0, stream,
                       h1, h2, uv0, Y1, 10240);

    hipLaunchKernelGGL(mid_kernel, dim3(1152), dim3(256), 0, stream,
                       Y1, W0, H1, h0, h1, uv0, H0a);

    hipLaunchKernelGGL(tail2_kernel, dim3(512), dim3(256), 0, stream,
                       H0a, H1, uv1, W1, fcW, outp);
}

// Round 3
// 81.425 us; speedup vs baseline: 1.5984x; 1.0214x over previous
//
#include <hip/hip_runtime.h>

#define LRELU_SLOPE 0.2f

// ---------------- workspace layout (float offsets) ----------------
#define OFF_UV0  0u         // u0[2][128], v0[2][128]           (512)
#define OFF_U1   512u       // u1[2][256]                       (512)
#define OFF_V1   1024u      // v1[2][256]                       (512)
#define OFF_P    1536u      // P[h][g]  (neigh logits, layer1)  (512)
#define OFF_PP   2048u      // P'[h][g] (self  logits, layer1)  (512)
#define OFF_Q    4096u      // Q[2][256][128]                   (65536)
#define OFF_R    69632u     // R[2][256][128]                   (65536)
#define OFF_Y1   135168u    // Y1[10240][256]
#define OFF_Y0   2756608u   // Y0[1024][256]

__device__ __forceinline__ float dot4(float4 a, float4 b) {
    return a.x * b.x + a.y * b.y + a.z * b.z + a.w * b.w;
}

// ============ prepA: uv0, u1/v1, Q = W1 @ fcW-block ============
__global__ __launch_bounds__(256)
void prepA_kernel(const float* __restrict__ W0, const float* __restrict__ as0,
                  const float* __restrict__ an0,
                  const float* __restrict__ W1, const float* __restrict__ as1,
                  const float* __restrict__ an1,
                  const float* __restrict__ fcW, float* __restrict__ ws) {
    __shared__ float s[32 * 129];
    const int b = blockIdx.x;
    const int t = threadIdx.x;
    if (b < 192) {
        // wave-per-row folds: rows 0..255 -> uv0; rows 256..767 -> u1/v1
        const int wid = b * 4 + (t >> 6);
        const int lane = t & 63;
        const float *wrow, *as, *an;
        if (wid < 256) {
            wrow = W0 + (size_t)wid * 128;
            int h = wid >> 7;
            as = as0 + h * 128; an = an0 + h * 128;
        } else {
            int g = wid - 256;
            wrow = W1 + (size_t)g * 128;
            int h = g >> 8;
            as = as1 + h * 128; an = an1 + h * 128;
        }
        float2 w = *(const float2*)(wrow + 2 * lane);
        float2 sv = *(const float2*)(as + 2 * lane);
        float2 nv = *(const float2*)(an + 2 * lane);
        float au = w.x * sv.x + w.y * sv.y;
        float av = w.x * nv.x + w.y * nv.y;
        #pragma unroll
        for (int off = 32; off > 0; off >>= 1) {
            au += __shfl_xor(au, off);
            av += __shfl_xor(av, off);
        }
        if (lane == 0) {
            if (wid < 256) { ws[OFF_UV0 + wid] = au; ws[OFF_UV0 + 256 + wid] = av; }
            else { int g = wid - 256; ws[OFF_U1 + g] = au; ws[OFF_V1 + g] = av; }
        }
    } else {
        // Q[h][g][o] = sum_d2 W1[h][g][d2] * fcW[h*128+d2][o]; 16 tiles of 32 g-rows
        const int idx = b - 192;
        const int h = idx >> 3, g0 = (idx & 7) * 32;
        const float* Wh = W1 + (size_t)h * 32768;
        for (int ii = t * 4; ii < 32 * 128; ii += 1024) {
            int i = ii >> 7, d = ii & 127;
            float4 g4 = *(const float4*)(Wh + (size_t)(g0 + i) * 128 + d);
            s[i * 129 + d + 0] = g4.x;
            s[i * 129 + d + 1] = g4.y;
            s[i * 129 + d + 2] = g4.z;
            s[i * 129 + d + 3] = g4.w;
        }
        __syncthreads();
        const int dg = t & 31, rg = t >> 5;
        float4 acc[4];
        #pragma unroll
        for (int j = 0; j < 4; ++j) acc[j] = make_float4(0.f, 0.f, 0.f, 0.f);
        const float* fp = fcW + (size_t)h * 16384 + 4 * dg;
        #pragma unroll 4
        for (int d2 = 0; d2 < 128; ++d2) {
            float4 f4 = *(const float4*)(fp + (size_t)d2 * 128);
            #pragma unroll
            for (int j = 0; j < 4; ++j) {
                float x = s[(rg * 4 + j) * 129 + d2];
                acc[j].x += x * f4.x; acc[j].y += x * f4.y;
                acc[j].z += x * f4.z; acc[j].w += x * f4.w;
            }
        }
        float* Qp = ws + OFF_Q + (size_t)h * 32768;
        #pragma unroll
        for (int j = 0; j < 4; ++j)
            *(float4*)(Qp + (size_t)(g0 + rg * 4 + j) * 128 + 4 * dg) = acc[j];
    }
}

// ============ BIG: attn25 -> Y1 | attn10 -> Y0 | P,P' folds | R tiles ============
__global__ __launch_bounds__(256)
void big_kernel(const float* __restrict__ h0, const float* __restrict__ h1,
                const float* __restrict__ h2, const float* __restrict__ W0,
                float* __restrict__ ws) {
    __shared__ float smem[4160];
    __shared__ float en25[26][2];
    __shared__ float al25[25][2];
    __shared__ float en10[2][11][2];
    __shared__ float al10[2][10][2];
    const int b = blockIdx.x;
    const int t = threadIdx.x;
    const float* uv0 = ws + OFF_UV0;

    if (b < 10240) {
        // ---- GAT level1: self=h1[m], neigh=h2 rows m*25..m*25+24 -> Y1[m][256]
        const int m = b;
        const int rlane = t & 31;
        const int rgrp = t >> 5;
        const float4 su0 = *(const float4*)(uv0 + 0 + 4 * rlane);
        const float4 su1 = *(const float4*)(uv0 + 128 + 4 * rlane);
        const float4 nv0 = *(const float4*)(uv0 + 256 + 4 * rlane);
        const float4 nv1 = *(const float4*)(uv0 + 384 + 4 * rlane);
        const float* xnp = h2 + (size_t)m * 25 * 128;
        const float* xsp = h1 + (size_t)m * 128;
        float4 g[4];
        #pragma unroll
        for (int i = 0; i < 4; ++i) {
            int r = rgrp + 8 * i;
            if (r <= 25) {
                const float* src = (r < 25) ? (xnp + (size_t)r * 128) : xsp;
                g[i] = *(const float4*)(src + 4 * rlane);
            }
        }
        #pragma unroll
        for (int i = 0; i < 4; ++i) {
            int r = rgrp + 8 * i;
            if (r <= 25) {
                if (r < 25) *(float4*)(&smem[r * 128 + 4 * rlane]) = g[i];
                float p0 = dot4(g[i], (r < 25) ? nv0 : su0);
                float p1 = dot4(g[i], (r < 25) ? nv1 : su1);
                #pragma unroll
                for (int off = 16; off > 0; off >>= 1) {
                    p0 += __shfl_xor(p0, off);
                    p1 += __shfl_xor(p1, off);
                }
                if (rlane == 0) { en25[r][0] = p0; en25[r][1] = p1; }
            }
        }
        __syncthreads();
        if (t < 64) {
            int h = t >> 5, k = t & 31;
            float e = -1e30f;
            if (k < 25) {
                float z = en25[25][h] + en25[k][h];
                e = (z >= 0.f) ? z : LRELU_SLOPE * z;
            }
            float mx = e;
            #pragma unroll
            for (int off = 16; off > 0; off >>= 1) mx = fmaxf(mx, __shfl_xor(mx, off));
            float ex = (k < 25) ? __expf(e - mx) : 0.f;
            float sm = ex;
            #pragma unroll
            for (int off = 16; off > 0; off >>= 1) sm += __shfl_xor(sm, off);
            if (k < 25) al25[k][h] = ex / sm;
        }
        __syncthreads();
        const int h = t >> 7, f = t & 127;
        float acc = 0.f;
        #pragma unroll
        for (int k = 0; k < 25; ++k) acc += al25[k][h] * smem[k * 128 + f];
        ws[OFF_Y1 + (size_t)m * 256 + t] = acc;
    } else if (b < 10752) {
        // ---- GAT level0: self=h0, neigh=h1 (K=10), 2 targets -> Y0
        const int m0 = (b - 10240) * 2;
        const int rlane = t & 31;
        const int rg = t >> 5;
        const float4 su0 = *(const float4*)(uv0 + 0 + 4 * rlane);
        const float4 su1 = *(const float4*)(uv0 + 128 + 4 * rlane);
        const float4 nv0 = *(const float4*)(uv0 + 256 + 4 * rlane);
        const float4 nv1 = *(const float4*)(uv0 + 384 + 4 * rlane);
        float4 g[3];
        #pragma unroll
        for (int i = 0; i < 3; ++i) {
            int rho = rg + 8 * i;
            if (rho < 22) {
                int r = rho / 11, k = rho % 11;
                int m = m0 + r;
                const float* src = (k < 10) ? (h1 + ((size_t)m * 10 + k) * 128)
                                            : (h0 + (size_t)m * 128);
                g[i] = *(const float4*)(src + 4 * rlane);
            }
        }
        #pragma unroll
        for (int i = 0; i < 3; ++i) {
            int rho = rg + 8 * i;
            if (rho < 22) {
                int r = rho / 11, k = rho % 11;
                *(float4*)(&smem[rho * 128 + 4 * rlane]) = g[i];
                float p0 = dot4(g[i], (k < 10) ? nv0 : su0);
                float p1 = dot4(g[i], (k < 10) ? nv1 : su1);
                #pragma unroll
                for (int off = 16; off > 0; off >>= 1) {
                    p0 += __shfl_xor(p0, off);
                    p1 += __shfl_xor(p1, off);
                }
                if (rlane == 0) { en10[r][k][0] = p0; en10[r][k][1] = p1; }
            }
        }
        __syncthreads();
        if (t < 128) {
            int r = t >> 6, h = (t >> 5) & 1, k = t & 31;
            float e = -1e30f;
            if (k < 10) {
                float z = en10[r][10][h] + en10[r][k][h];
                e = (z >= 0.f) ? z : LRELU_SLOPE * z;
            }
            float mx = e;
            #pragma unroll
            for (int off = 16; off > 0; off >>= 1) mx = fmaxf(mx, __shfl_xor(mx, off));
            float ex = (k < 10) ? __expf(e - mx) : 0.f;
            float sm = ex;
            #pragma unroll
            for (int off = 16; off > 0; off >>= 1) sm += __shfl_xor(sm, off);
            if (k < 10) al10[r][k][h] = ex / sm;
        }
        __syncthreads();
        #pragma unroll
        for (int i = 0; i < 2; ++i) {
            int c = t + 256 * i;
            int r = c >> 8, rem = c & 255, h = rem >> 7, f = rem & 127;
            float acc = 0.f;
            #pragma unroll
            for (int k = 0; k < 10; ++k) acc += al10[r][k][h] * smem[(r * 11 + k) * 128 + f];
            ws[OFF_Y0 + (size_t)(m0 + r) * 256 + rem] = acc;
        }
    } else if (b < 10880) {
        // ---- P/P' folds: wave per (h,g) pair; P'[h][g]=W0rowfold(u1), P=fold(v1)
        const int wid = (b - 10752) * 4 + (t >> 6);   // [0,512)
        const int lane = t & 63;
        const int h = wid >> 8, rest = wid & 255;     // rest = h0*128+f
        const int h0 = rest >> 7;
        const float* wrow = W0 + (size_t)rest * 128;  // == W0[h0][f][*]
        float2 w2 = *(const float2*)(wrow + 2 * lane);
        float2 su = *(const float2*)(ws + OFF_U1 + h * 256 + h0 * 128 + 2 * lane);
        float2 sv = *(const float2*)(ws + OFF_V1 + h * 256 + h0 * 128 + 2 * lane);
        float pu = w2.x * su.x + w2.y * su.y;
        float pv = w2.x * sv.x + w2.y * sv.y;
        #pragma unroll
        for (int off = 32; off > 0; off >>= 1) {
            pu += __shfl_xor(pu, off);
            pv += __shfl_xor(pv, off);
        }
        if (lane == 0) { ws[OFF_PP + wid] = pu; ws[OFF_P + wid] = pv; }
    } else {
        // ---- R[h][h0*128+f][o] = sum_d W0[h0][f][d] * Q[h][h0*128+d][o]; 16 tiles
        const int idx = b - 10880;
        const int h = idx >> 3;
        const int h0 = (idx >> 2) & 1;
        const int f0 = (idx & 3) * 32;
        const float* W0h = W0 + (size_t)h0 * 16384;
        for (int ii = t * 4; ii < 32 * 128; ii += 1024) {
            int i = ii >> 7, d = ii & 127;
            float4 g4 = *(const float4*)(W0h + (size_t)(f0 + i) * 128 + d);
            smem[i * 129 + d + 0] = g4.x;
            smem[i * 129 + d + 1] = g4.y;
            smem[i * 129 + d + 2] = g4.z;
            smem[i * 129 + d + 3] = g4.w;
        }
        __syncthreads();
        const int dg = t & 31, rg = t >> 5;
        float4 acc[4];
        #pragma unroll
        for (int j = 0; j < 4; ++j) acc[j] = make_float4(0.f, 0.f, 0.f, 0.f);
        const float* Qp = ws + OFF_Q + (size_t)h * 32768 + (size_t)h0 * 16384 + 4 * dg;
        #pragma unroll 4
        for (int d = 0; d < 128; ++d) {
            float4 q4 = *(const float4*)(Qp + (size_t)d * 128);
            #pragma unroll
            for (int j = 0; j < 4; ++j) {
                float x = smem[(rg * 4 + j) * 129 + d];
                acc[j].x += x * q4.x; acc[j].y += x * q4.y;
                acc[j].z += x * q4.z; acc[j].w += x * q4.w;
            }
        }
        float* Rp = ws + OFF_R + (size_t)h * 32768 + (size_t)h0 * 16384;
        #pragma unroll
        for (int j = 0; j < 4; ++j)
            *(float4*)(Rp + (size_t)(f0 + rg * 4 + j) * 128 + 4 * dg) = acc[j];
    }
}

// ============ FINAL: layer1 attn via P/P' + out = ybar @ R; 2 targets/block ============
__global__ __launch_bounds__(256)
void final_kernel(const float* __restrict__ ws, float* __restrict__ out) {
    __shared__ float xn[22 * 256];
    __shared__ float yb[1024];
    __shared__ float en[2][11][2];
    __shared__ float al[2][10][2];
    const int t = threadIdx.x;
    const int m0 = blockIdx.x * 2;
    const int rlane = t & 63;
    const int rg = t >> 6;
    const float* P  = ws + OFF_P;
    const float* Pp = ws + OFF_PP;
    const float* Y1 = ws + OFF_Y1;
    const float* Y0 = ws + OFF_Y0;
    const float4 su0 = *(const float4*)(Pp + 0 + 4 * rlane);
    const float4 su1 = *(const float4*)(Pp + 256 + 4 * rlane);
    const float4 nv0 = *(const float4*)(P + 0 + 4 * rlane);
    const float4 nv1 = *(const float4*)(P + 256 + 4 * rlane);
    float4 g[6];
    #pragma unroll
    for (int i = 0; i < 6; ++i) {
        int rho = rg + 4 * i;
        if (rho < 22) {
            int r = rho / 11, k = rho % 11;
            int m = m0 + r;
            const float* src = (k < 10) ? (Y1 + ((size_t)m * 10 + k) * 256)
                                        : (Y0 + (size_t)m * 256);
            g[i] = *(const float4*)(src + 4 * rlane);
        }
    }
    #pragma unroll
    for (int i = 0; i < 6; ++i) {
        int rho = rg + 4 * i;
        if (rho < 22) {
            int r = rho / 11, k = rho % 11;
            *(float4*)(&xn[rho * 256 + 4 * rlane]) = g[i];
            float p0 = dot4(g[i], (k < 10) ? nv0 : su0);
            float p1 = dot4(g[i], (k < 10) ? nv1 : su1);
            #pragma unroll
            for (int off = 32; off > 0; off >>= 1) {
                p0 += __shfl_xor(p0, off);
                p1 += __shfl_xor(p1, off);
            }
            if (rlane == 0) { en[r][k][0] = p0; en[r][k][1] = p1; }
        }
    }
    __syncthreads();
    if (t < 128) {
        int r = t >> 6, h = (t >> 5) & 1, k = t & 31;
        float e = -1e30f;
        if (k < 10) {
            float z = en[r][10][h] + en[r][k][h];
            e = (z >= 0.f) ? z : LRELU_SLOPE * z;
        }
        float mx = e;
        #pragma unroll
        for (int off = 16; off > 0; off >>= 1) mx = fmaxf(mx, __shfl_xor(mx, off));
        float ex = (k < 10) ? __expf(e - mx) : 0.f;
        float sm = ex;
        #pragma unroll
        for (int off = 16; off > 0; off >>= 1) sm += __shfl_xor(sm, off);
        if (k < 10) al[r][k][h] = ex / sm;
    }
    __syncthreads();
    #pragma unroll
    for (int i = 0; i < 4; ++i) {
        int c = t + 256 * i;                 // [0,1024): [r][h][f]
        int r = c >> 9, rem = c & 511, h = rem >> 8, f = rem & 255;
        float acc = 0.f;
        #pragma unroll
        for (int k = 0; k < 10; ++k) acc += al[r][k][h] * xn[(r * 11 + k) * 256 + f];
        yb[c] = acc;
    }
    __syncthreads();
    const int r = t >> 7, o = t & 127;
    const float* Rv = ws + OFF_R + o;
    const float* yy = yb + r * 512;
    float acc = 0.f;
    #pragma unroll 8
    for (int gi = 0; gi < 512; ++gi) acc += yy[gi] * Rv[(size_t)gi * 128];
    out[(size_t)(m0 + r) * 128 + o] = acc;
}

extern "C" void kernel_launch(void* const* d_in, const int* in_sizes, int n_in,
                              void* d_out, int out_size, void* d_ws, size_t ws_size,
                              hipStream_t stream) {
    const float* h0  = (const float*)d_in[0];
    const float* h1  = (const float*)d_in[1];
    const float* h2  = (const float*)d_in[2];
    const float* W0  = (const float*)d_in[3];
    const float* as0 = (const float*)d_in[4];
    const float* an0 = (const float*)d_in[5];
    const float* W1  = (const float*)d_in[6];
    const float* as1 = (const float*)d_in[7];
    const float* an1 = (const float*)d_in[8];
    const float* fcW = (const float*)d_in[9];
    float* outp = (float*)d_out;
    float* ws = (float*)d_ws;

    hipLaunchKernelGGL(prepA_kernel, dim3(208), dim3(256), 0, stream,
                       W0, as0, an0, W1, as1, an1, fcW, ws);
    hipLaunchKernelGGL(big_kernel, dim3(10896), dim3(256), 0, stream,
                       h0, h1, h2, W0, ws);
    hipLaunchKernelGGL(final_kernel, dim3(512), dim3(256), 0, stream,
                       ws, outp);
}

// Round 4
// 75.135 us; speedup vs baseline: 1.7323x; 1.0837x over previous
//
#include <hip/hip_runtime.h>

#define LRELU_SLOPE 0.2f

// ---------------- workspace layout (float offsets) ----------------
#define OFF_UV0  0u         // u0[2][128], v0[2][128]           (512)
#define OFF_U1   512u       // u1[2][256]                       (512)
#define OFF_V1   1024u      // v1[2][256]                       (512)
#define OFF_P    1536u      // P[h][g]  (neigh logits, layer1)  (512)
#define OFF_PP   2048u      // P'[h][g] (self  logits, layer1)  (512)
#define OFF_Q    4096u      // Q[2][256][128]                   (65536)
#define OFF_R    69632u     // R[2][256][128]                   (65536)
#define OFF_Y1   135168u    // Y1[10240][256]
#define OFF_Y0   2756608u   // Y0[1024][256]

__device__ __forceinline__ float dot4(float4 a, float4 b) {
    return a.x * b.x + a.y * b.y + a.z * b.z + a.w * b.w;
}

// ============ prepA: uv0, u1/v1, Q = W1 @ fcW-block ============
__global__ __launch_bounds__(256)
void prepA_kernel(const float* __restrict__ W0, const float* __restrict__ as0,
                  const float* __restrict__ an0,
                  const float* __restrict__ W1, const float* __restrict__ as1,
                  const float* __restrict__ an1,
                  const float* __restrict__ fcW, float* __restrict__ ws) {
    __shared__ float s[32 * 129];
    const int b = blockIdx.x;
    const int t = threadIdx.x;
    if (b < 192) {
        const int wid = b * 4 + (t >> 6);
        const int lane = t & 63;
        const float *wrow, *as, *an;
        if (wid < 256) {
            wrow = W0 + (size_t)wid * 128;
            int h = wid >> 7;
            as = as0 + h * 128; an = an0 + h * 128;
        } else {
            int g = wid - 256;
            wrow = W1 + (size_t)g * 128;
            int h = g >> 8;
            as = as1 + h * 128; an = an1 + h * 128;
        }
        float2 w = *(const float2*)(wrow + 2 * lane);
        float2 sv = *(const float2*)(as + 2 * lane);
        float2 nv = *(const float2*)(an + 2 * lane);
        float au = w.x * sv.x + w.y * sv.y;
        float av = w.x * nv.x + w.y * nv.y;
        #pragma unroll
        for (int off = 32; off > 0; off >>= 1) {
            au += __shfl_xor(au, off);
            av += __shfl_xor(av, off);
        }
        if (lane == 0) {
            if (wid < 256) { ws[OFF_UV0 + wid] = au; ws[OFF_UV0 + 256 + wid] = av; }
            else { int g = wid - 256; ws[OFF_U1 + g] = au; ws[OFF_V1 + g] = av; }
        }
    } else {
        // Q[h][g][o] = sum_d2 W1[h][g][d2] * fcW[h*128+d2][o]
        const int idx = b - 192;
        const int h = idx >> 3, g0 = (idx & 7) * 32;
        const float* Wh = W1 + (size_t)h * 32768;
        for (int ii = t * 4; ii < 32 * 128; ii += 1024) {
            int i = ii >> 7, d = ii & 127;
            float4 g4 = *(const float4*)(Wh + (size_t)(g0 + i) * 128 + d);
            s[i * 129 + d + 0] = g4.x;
            s[i * 129 + d + 1] = g4.y;
            s[i * 129 + d + 2] = g4.z;
            s[i * 129 + d + 3] = g4.w;
        }
        __syncthreads();
        const int dg = t & 31, rg = t >> 5;
        float4 acc[4];
        #pragma unroll
        for (int j = 0; j < 4; ++j) acc[j] = make_float4(0.f, 0.f, 0.f, 0.f);
        const float* fp = fcW + (size_t)h * 16384 + 4 * dg;
        #pragma unroll 4
        for (int d2 = 0; d2 < 128; ++d2) {
            float4 f4 = *(const float4*)(fp + (size_t)d2 * 128);
            #pragma unroll
            for (int j = 0; j < 4; ++j) {
                float x = s[(rg * 4 + j) * 129 + d2];
                acc[j].x += x * f4.x; acc[j].y += x * f4.y;
                acc[j].z += x * f4.z; acc[j].w += x * f4.w;
            }
        }
        float* Qp = ws + OFF_Q + (size_t)h * 32768;
        #pragma unroll
        for (int j = 0; j < 4; ++j)
            *(float4*)(Qp + (size_t)(g0 + rg * 4 + j) * 128 + 4 * dg) = acc[j];
    }
}

// ============ big2: wave-per-target attn (no LDS, no barriers) + folds ============
__global__ __launch_bounds__(256)
void big2_kernel(const float* __restrict__ h0, const float* __restrict__ h1,
                 const float* __restrict__ h2, const float* __restrict__ W0,
                 float* __restrict__ ws) {
    const int b = blockIdx.x;
    const int t = threadIdx.x;
    const float* uv0 = ws + OFF_UV0;

    if (b < 2560) {
        // ---- attn25: one wave per target, all state in registers ----
        const int lane = t & 63;
        const int half = lane >> 5;         // 0: even rows, 1: odd rows
        const int fl = lane & 31;           // float4 slot within row
        const int m = b * 4 + (t >> 6);
        const float* xnp = h2 + (size_t)m * 3200;
        const float* xsp = h1 + (size_t)m * 128;
        const float4 u0 = *(const float4*)(uv0 + 0 + 4 * fl);
        const float4 u1 = *(const float4*)(uv0 + 128 + 4 * fl);
        const float4 v0 = *(const float4*)(uv0 + 256 + 4 * fl);
        const float4 v1 = *(const float4*)(uv0 + 384 + 4 * fl);

        float4 xr[13];
        // iter 0: rows 24 (low half, neighbor) / 25 = self (high half)
        {
            const float* sp = half ? xsp : (xnp + 24 * 128);
            xr[0] = *(const float4*)(sp + 4 * fl);
        }
        #pragma unroll
        for (int i = 1; i < 13; ++i)
            xr[i] = *(const float4*)(xnp + (size_t)(2 * (i - 1) + half) * 128 + 4 * fl);

        float z0[13], z1[13];
        #pragma unroll
        for (int i = 0; i < 13; ++i) {
            bool selfrow = (i == 0) && half;
            float p0 = dot4(xr[i], selfrow ? u0 : v0);
            float p1 = dot4(xr[i], selfrow ? u1 : v1);
            #pragma unroll
            for (int off = 16; off > 0; off >>= 1) {
                p0 += __shfl_xor(p0, off);
                p1 += __shfl_xor(p1, off);
            }
            z0[i] = p0; z1[i] = p1;
        }
        const float es0 = __shfl(z0[0], 32);
        const float es1 = __shfl(z1[0], 32);
        float mx0 = -1e30f, mx1 = -1e30f;
        #pragma unroll
        for (int i = 0; i < 13; ++i) {
            if (i == 0 && half) { z0[i] = -1e30f; z1[i] = -1e30f; }
            else {
                float a = es0 + z0[i]; a = (a >= 0.f) ? a : LRELU_SLOPE * a;
                float c = es1 + z1[i]; c = (c >= 0.f) ? c : LRELU_SLOPE * c;
                z0[i] = a; z1[i] = c;
                mx0 = fmaxf(mx0, a); mx1 = fmaxf(mx1, c);
            }
        }
        mx0 = fmaxf(mx0, __shfl_xor(mx0, 32));
        mx1 = fmaxf(mx1, __shfl_xor(mx1, 32));
        float s0 = 0.f, s1 = 0.f;
        float4 A0 = make_float4(0.f, 0.f, 0.f, 0.f);
        float4 A1 = make_float4(0.f, 0.f, 0.f, 0.f);
        #pragma unroll
        for (int i = 0; i < 13; ++i) {
            float e0 = __expf(z0[i] - mx0);
            float e1 = __expf(z1[i] - mx1);
            s0 += e0; s1 += e1;
            A0.x += e0 * xr[i].x; A0.y += e0 * xr[i].y;
            A0.z += e0 * xr[i].z; A0.w += e0 * xr[i].w;
            A1.x += e1 * xr[i].x; A1.y += e1 * xr[i].y;
            A1.z += e1 * xr[i].z; A1.w += e1 * xr[i].w;
        }
        s0 += __shfl_xor(s0, 32); s1 += __shfl_xor(s1, 32);
        A0.x += __shfl_xor(A0.x, 32); A0.y += __shfl_xor(A0.y, 32);
        A0.z += __shfl_xor(A0.z, 32); A0.w += __shfl_xor(A0.w, 32);
        A1.x += __shfl_xor(A1.x, 32); A1.y += __shfl_xor(A1.y, 32);
        A1.z += __shfl_xor(A1.z, 32); A1.w += __shfl_xor(A1.w, 32);
        const float inv = 1.f / (half ? s1 : s0);
        const float4 S = half ? A1 : A0;
        float4 o;
        o.x = S.x * inv; o.y = S.y * inv; o.z = S.z * inv; o.w = S.w * inv;
        *(float4*)(ws + OFF_Y1 + (size_t)m * 256 + half * 128 + 4 * fl) = o;
    } else if (b < 2816) {
        // ---- attn10: one wave per target (self loaded by both halves at iter 0)
        const int lane = t & 63;
        const int half = lane >> 5;
        const int fl = lane & 31;
        const int m = (b - 2560) * 4 + (t >> 6);
        const float* xnp = h1 + (size_t)m * 1280;
        const float* xsp = h0 + (size_t)m * 128;
        const float4 u0 = *(const float4*)(uv0 + 0 + 4 * fl);
        const float4 u1 = *(const float4*)(uv0 + 128 + 4 * fl);
        const float4 v0 = *(const float4*)(uv0 + 256 + 4 * fl);
        const float4 v1 = *(const float4*)(uv0 + 384 + 4 * fl);

        float4 xr[6];
        xr[0] = *(const float4*)(xsp + 4 * fl);     // self (both halves)
        #pragma unroll
        for (int i = 1; i < 6; ++i)
            xr[i] = *(const float4*)(xnp + (size_t)(2 * (i - 1) + half) * 128 + 4 * fl);

        float z0[6], z1[6];
        #pragma unroll
        for (int i = 0; i < 6; ++i) {
            float p0 = dot4(xr[i], (i == 0) ? u0 : v0);
            float p1 = dot4(xr[i], (i == 0) ? u1 : v1);
            #pragma unroll
            for (int off = 16; off > 0; off >>= 1) {
                p0 += __shfl_xor(p0, off);
                p1 += __shfl_xor(p1, off);
            }
            z0[i] = p0; z1[i] = p1;
        }
        const float es0 = z0[0];     // both halves computed the full self dot
        const float es1 = z1[0];
        float mx0 = -1e30f, mx1 = -1e30f;
        #pragma unroll
        for (int i = 0; i < 6; ++i) {
            if (i == 0) { z0[i] = -1e30f; z1[i] = -1e30f; }
            else {
                float a = es0 + z0[i]; a = (a >= 0.f) ? a : LRELU_SLOPE * a;
                float c = es1 + z1[i]; c = (c >= 0.f) ? c : LRELU_SLOPE * c;
                z0[i] = a; z1[i] = c;
                mx0 = fmaxf(mx0, a); mx1 = fmaxf(mx1, c);
            }
        }
        mx0 = fmaxf(mx0, __shfl_xor(mx0, 32));
        mx1 = fmaxf(mx1, __shfl_xor(mx1, 32));
        float s0 = 0.f, s1 = 0.f;
        float4 A0 = make_float4(0.f, 0.f, 0.f, 0.f);
        float4 A1 = make_float4(0.f, 0.f, 0.f, 0.f);
        #pragma unroll
        for (int i = 0; i < 6; ++i) {
            float e0 = __expf(z0[i] - mx0);
            float e1 = __expf(z1[i] - mx1);
            s0 += e0; s1 += e1;
            A0.x += e0 * xr[i].x; A0.y += e0 * xr[i].y;
            A0.z += e0 * xr[i].z; A0.w += e0 * xr[i].w;
            A1.x += e1 * xr[i].x; A1.y += e1 * xr[i].y;
            A1.z += e1 * xr[i].z; A1.w += e1 * xr[i].w;
        }
        s0 += __shfl_xor(s0, 32); s1 += __shfl_xor(s1, 32);
        A0.x += __shfl_xor(A0.x, 32); A0.y += __shfl_xor(A0.y, 32);
        A0.z += __shfl_xor(A0.z, 32); A0.w += __shfl_xor(A0.w, 32);
        A1.x += __shfl_xor(A1.x, 32); A1.y += __shfl_xor(A1.y, 32);
        A1.z += __shfl_xor(A1.z, 32); A1.w += __shfl_xor(A1.w, 32);
        const float inv = 1.f / (half ? s1 : s0);
        const float4 S = half ? A1 : A0;
        float4 o;
        o.x = S.x * inv; o.y = S.y * inv; o.z = S.z * inv; o.w = S.w * inv;
        *(float4*)(ws + OFF_Y0 + (size_t)m * 256 + half * 128 + 4 * fl) = o;
    } else if (b < 2944) {
        // ---- P/P' folds
        const int wid = (b - 2816) * 4 + (t >> 6);   // [0,512)
        const int lane = t & 63;
        const int h = wid >> 8, rest = wid & 255;
        const int h0i = rest >> 7;
        const float* wrow = W0 + (size_t)rest * 128;
        float2 w2 = *(const float2*)(wrow + 2 * lane);
        float2 su = *(const float2*)(ws + OFF_U1 + h * 256 + h0i * 128 + 2 * lane);
        float2 sv = *(const float2*)(ws + OFF_V1 + h * 256 + h0i * 128 + 2 * lane);
        float pu = w2.x * su.x + w2.y * su.y;
        float pv = w2.x * sv.x + w2.y * sv.y;
        #pragma unroll
        for (int off = 32; off > 0; off >>= 1) {
            pu += __shfl_xor(pu, off);
            pv += __shfl_xor(pv, off);
        }
        if (lane == 0) { ws[OFF_PP + wid] = pu; ws[OFF_P + wid] = pv; }
    } else {
        // ---- R tiles: R[h][h0*128+f][o] = sum_d W0[h0][f][d] * Q[h][h0*128+d][o]
        __shared__ float smem[4160];
        const int idx = b - 2944;
        const int h = idx >> 3;
        const int h0i = (idx >> 2) & 1;
        const int f0 = (idx & 3) * 32;
        const float* W0h = W0 + (size_t)h0i * 16384;
        for (int ii = t * 4; ii < 32 * 128; ii += 1024) {
            int i = ii >> 7, d = ii & 127;
            float4 g4 = *(const float4*)(W0h + (size_t)(f0 + i) * 128 + d);
            smem[i * 129 + d + 0] = g4.x;
            smem[i * 129 + d + 1] = g4.y;
            smem[i * 129 + d + 2] = g4.z;
            smem[i * 129 + d + 3] = g4.w;
        }
        __syncthreads();
        const int dg = t & 31, rg = t >> 5;
        float4 acc[4];
        #pragma unroll
        for (int j = 0; j < 4; ++j) acc[j] = make_float4(0.f, 0.f, 0.f, 0.f);
        const float* Qp = ws + OFF_Q + (size_t)h * 32768 + (size_t)h0i * 16384 + 4 * dg;
        #pragma unroll 4
        for (int d = 0; d < 128; ++d) {
            float4 q4 = *(const float4*)(Qp + (size_t)d * 128);
            #pragma unroll
            for (int j = 0; j < 4; ++j) {
                float x = smem[(rg * 4 + j) * 129 + d];
                acc[j].x += x * q4.x; acc[j].y += x * q4.y;
                acc[j].z += x * q4.z; acc[j].w += x * q4.w;
            }
        }
        float* Rp = ws + OFF_R + (size_t)h * 32768 + (size_t)h0i * 16384;
        #pragma unroll
        for (int j = 0; j < 4; ++j)
            *(float4*)(Rp + (size_t)(f0 + rg * 4 + j) * 128 + 4 * dg) = acc[j];
    }
}

// ============ FINAL: layer1 attn via P/P' + out = ybar @ R; 2 targets/block ============
__global__ __launch_bounds__(256)
void final_kernel(const float* __restrict__ ws, float* __restrict__ out) {
    __shared__ float xn[22 * 256];
    __shared__ float yb[1024];
    __shared__ float en[2][11][2];
    __shared__ float al[2][10][2];
    const int t = threadIdx.x;
    const int m0 = blockIdx.x * 2;
    const int rlane = t & 63;
    const int rg = t >> 6;
    const float* P  = ws + OFF_P;
    const float* Pp = ws + OFF_PP;
    const float* Y1 = ws + OFF_Y1;
    const float* Y0 = ws + OFF_Y0;
    const float4 su0 = *(const float4*)(Pp + 0 + 4 * rlane);
    const float4 su1 = *(const float4*)(Pp + 256 + 4 * rlane);
    const float4 nv0 = *(const float4*)(P + 0 + 4 * rlane);
    const float4 nv1 = *(const float4*)(P + 256 + 4 * rlane);
    float4 g[6];
    #pragma unroll
    for (int i = 0; i < 6; ++i) {
        int rho = rg + 4 * i;
        if (rho < 22) {
            int r = rho / 11, k = rho % 11;
            int m = m0 + r;
            const float* src = (k < 10) ? (Y1 + ((size_t)m * 10 + k) * 256)
                                        : (Y0 + (size_t)m * 256);
            g[i] = *(const float4*)(src + 4 * rlane);
        }
    }
    #pragma unroll
    for (int i = 0; i < 6; ++i) {
        int rho = rg + 4 * i;
        if (rho < 22) {
            int r = rho / 11, k = rho % 11;
            *(float4*)(&xn[rho * 256 + 4 * rlane]) = g[i];
            float p0 = dot4(g[i], (k < 10) ? nv0 : su0);
            float p1 = dot4(g[i], (k < 10) ? nv1 : su1);
            #pragma unroll
            for (int off = 32; off > 0; off >>= 1) {
                p0 += __shfl_xor(p0, off);
                p1 += __shfl_xor(p1, off);
            }
            if (rlane == 0) { en[r][k][0] = p0; en[r][k][1] = p1; }
        }
    }
    __syncthreads();
    if (t < 128) {
        int r = t >> 6, h = (t >> 5) & 1, k = t & 31;
        float e = -1e30f;
        if (k < 10) {
            float z = en[r][10][h] + en[r][k][h];
            e = (z >= 0.f) ? z : LRELU_SLOPE * z;
        }
        float mx = e;
        #pragma unroll
        for (int off = 16; off > 0; off >>= 1) mx = fmaxf(mx, __shfl_xor(mx, off));
        float ex = (k < 10) ? __expf(e - mx) : 0.f;
        float sm = ex;
        #pragma unroll
        for (int off = 16; off > 0; off >>= 1) sm += __shfl_xor(sm, off);
        if (k < 10) al[r][k][h] = ex / sm;
    }
    __syncthreads();
    #pragma unroll
    for (int i = 0; i < 4; ++i) {
        int c = t + 256 * i;
        int r = c >> 9, rem = c & 511, h = rem >> 8, f = rem & 255;
        float acc = 0.f;
        #pragma unroll
        for (int k = 0; k < 10; ++k) acc += al[r][k][h] * xn[(r * 11 + k) * 256 + f];
        yb[c] = acc;
    }
    __syncthreads();
    const int r = t >> 7, o = t & 127;
    const float* Rv = ws + OFF_R + o;
    const float* yy = yb + r * 512;
    float acc = 0.f;
    #pragma unroll 8
    for (int gi = 0; gi < 512; ++gi) acc += yy[gi] * Rv[(size_t)gi * 128];
    out[(size_t)(m0 + r) * 128 + o] = acc;
}

extern "C" void kernel_launch(void* const* d_in, const int* in_sizes, int n_in,
                              void* d_out, int out_size, void* d_ws, size_t ws_size,
                              hipStream_t stream) {
    const float* h0  = (const float*)d_in[0];
    const float* h1  = (const float*)d_in[1];
    const float* h2  = (const float*)d_in[2];
    const float* W0  = (const float*)d_in[3];
    const float* as0 = (const float*)d_in[4];
    const float* an0 = (const float*)d_in[5];
    const float* W1  = (const float*)d_in[6];
    const float* as1 = (const float*)d_in[7];
    const float* an1 = (const float*)d_in[8];
    const float* fcW = (const float*)d_in[9];
    float* outp = (float*)d_out;
    float* ws = (float*)d_ws;

    hipLaunchKernelGGL(prepA_kernel, dim3(208), dim3(256), 0, stream,
                       W0, as0, an0, W1, as1, an1, fcW, ws);
    hipLaunchKernelGGL(big2_kernel, dim3(2960), dim3(256), 0, stream,
                       h0, h1, h2, W0, ws);
    hipLaunchKernelGGL(final_kernel, dim3(512), dim3(256), 0, stream,
                       ws, outp);
}

// Round 5
// 66.874 us; speedup vs baseline: 1.9462x; 1.1235x over previous
//
#include <hip/hip_runtime.h>

#define LRELU_SLOPE 0.2f

// ---------------- workspace layout (float offsets) ----------------
#define OFF_UV0  0u         // u0[2][128], v0[2][128]           (512)
#define OFF_U1   512u       // u1[2][256]                       (512)
#define OFF_V1   1024u      // v1[2][256]                       (512)
#define OFF_P    1536u      // P[h][g]  (neigh logits, layer1)  (512)
#define OFF_PP   2048u      // P'[h][g] (self  logits, layer1)  (512)
#define OFF_Q    4096u      // Q[2][256][128]                   (65536)
#define OFF_R    69632u     // R[2][256][128]                   (65536)
#define OFF_Y1   135168u    // Y1[10240][256]
#define OFF_Y0   2756608u   // Y0[1024][256]

__device__ __forceinline__ float dot4(float4 a, float4 b) {
    return a.x * b.x + a.y * b.y + a.z * b.z + a.w * b.w;
}

// ============ prepA: uv0, u1/v1, Q = W1 @ fcW-block ============
__global__ __launch_bounds__(256)
void prepA_kernel(const float* __restrict__ W0, const float* __restrict__ as0,
                  const float* __restrict__ an0,
                  const float* __restrict__ W1, const float* __restrict__ as1,
                  const float* __restrict__ an1,
                  const float* __restrict__ fcW, float* __restrict__ ws) {
    __shared__ float s[32 * 129];
    const int b = blockIdx.x;
    const int t = threadIdx.x;
    if (b < 192) {
        const int wid = b * 4 + (t >> 6);
        const int lane = t & 63;
        const float *wrow, *as, *an;
        if (wid < 256) {
            wrow = W0 + (size_t)wid * 128;
            int h = wid >> 7;
            as = as0 + h * 128; an = an0 + h * 128;
        } else {
            int g = wid - 256;
            wrow = W1 + (size_t)g * 128;
            int h = g >> 8;
            as = as1 + h * 128; an = an1 + h * 128;
        }
        float2 w = *(const float2*)(wrow + 2 * lane);
        float2 sv = *(const float2*)(as + 2 * lane);
        float2 nv = *(const float2*)(an + 2 * lane);
        float au = w.x * sv.x + w.y * sv.y;
        float av = w.x * nv.x + w.y * nv.y;
        #pragma unroll
        for (int off = 32; off > 0; off >>= 1) {
            au += __shfl_xor(au, off);
            av += __shfl_xor(av, off);
        }
        if (lane == 0) {
            if (wid < 256) { ws[OFF_UV0 + wid] = au; ws[OFF_UV0 + 256 + wid] = av; }
            else { int g = wid - 256; ws[OFF_U1 + g] = au; ws[OFF_V1 + g] = av; }
        }
    } else {
        // Q[h][g][o] = sum_d2 W1[h][g][d2] * fcW[h*128+d2][o]
        const int idx = b - 192;
        const int h = idx >> 3, g0 = (idx & 7) * 32;
        const float* Wh = W1 + (size_t)h * 32768;
        for (int ii = t * 4; ii < 32 * 128; ii += 1024) {
            int i = ii >> 7, d = ii & 127;
            float4 g4 = *(const float4*)(Wh + (size_t)(g0 + i) * 128 + d);
            s[i * 129 + d + 0] = g4.x;
            s[i * 129 + d + 1] = g4.y;
            s[i * 129 + d + 2] = g4.z;
            s[i * 129 + d + 3] = g4.w;
        }
        __syncthreads();
        const int dg = t & 31, rg = t >> 5;
        float4 acc[4];
        #pragma unroll
        for (int j = 0; j < 4; ++j) acc[j] = make_float4(0.f, 0.f, 0.f, 0.f);
        const float* fp = fcW + (size_t)h * 16384 + 4 * dg;
        #pragma unroll 4
        for (int d2 = 0; d2 < 128; ++d2) {
            float4 f4 = *(const float4*)(fp + (size_t)d2 * 128);
            #pragma unroll
            for (int j = 0; j < 4; ++j) {
                float x = s[(rg * 4 + j) * 129 + d2];
                acc[j].x += x * f4.x; acc[j].y += x * f4.y;
                acc[j].z += x * f4.z; acc[j].w += x * f4.w;
            }
        }
        float* Qp = ws + OFF_Q + (size_t)h * 32768;
        #pragma unroll
        for (int j = 0; j < 4; ++j)
            *(float4*)(Qp + (size_t)(g0 + rg * 4 + j) * 128 + 4 * dg) = acc[j];
    }
}

// ============ big2: wave-per-target attn (no LDS, no barriers) + folds ============
__global__ __launch_bounds__(256)
void big2_kernel(const float* __restrict__ h0, const float* __restrict__ h1,
                 const float* __restrict__ h2, const float* __restrict__ W0,
                 float* __restrict__ ws) {
    const int b = blockIdx.x;
    const int t = threadIdx.x;
    const float* uv0 = ws + OFF_UV0;

    if (b < 2560) {
        // ---- attn25: one wave per target, all state in registers ----
        const int lane = t & 63;
        const int half = lane >> 5;         // 0: even rows, 1: odd rows
        const int fl = lane & 31;           // float4 slot within row
        const int m = b * 4 + (t >> 6);
        const float* xnp = h2 + (size_t)m * 3200;
        const float* xsp = h1 + (size_t)m * 128;
        const float4 u0 = *(const float4*)(uv0 + 0 + 4 * fl);
        const float4 u1 = *(const float4*)(uv0 + 128 + 4 * fl);
        const float4 v0 = *(const float4*)(uv0 + 256 + 4 * fl);
        const float4 v1 = *(const float4*)(uv0 + 384 + 4 * fl);

        float4 xr[13];
        {
            const float* sp = half ? xsp : (xnp + 24 * 128);
            xr[0] = *(const float4*)(sp + 4 * fl);
        }
        #pragma unroll
        for (int i = 1; i < 13; ++i)
            xr[i] = *(const float4*)(xnp + (size_t)(2 * (i - 1) + half) * 128 + 4 * fl);

        float z0[13], z1[13];
        #pragma unroll
        for (int i = 0; i < 13; ++i) {
            bool selfrow = (i == 0) && half;
            float p0 = dot4(xr[i], selfrow ? u0 : v0);
            float p1 = dot4(xr[i], selfrow ? u1 : v1);
            #pragma unroll
            for (int off = 16; off > 0; off >>= 1) {
                p0 += __shfl_xor(p0, off);
                p1 += __shfl_xor(p1, off);
            }
            z0[i] = p0; z1[i] = p1;
        }
        const float es0 = __shfl(z0[0], 32);
        const float es1 = __shfl(z1[0], 32);
        float mx0 = -1e30f, mx1 = -1e30f;
        #pragma unroll
        for (int i = 0; i < 13; ++i) {
            if (i == 0 && half) { z0[i] = -1e30f; z1[i] = -1e30f; }
            else {
                float a = es0 + z0[i]; a = (a >= 0.f) ? a : LRELU_SLOPE * a;
                float c = es1 + z1[i]; c = (c >= 0.f) ? c : LRELU_SLOPE * c;
                z0[i] = a; z1[i] = c;
                mx0 = fmaxf(mx0, a); mx1 = fmaxf(mx1, c);
            }
        }
        mx0 = fmaxf(mx0, __shfl_xor(mx0, 32));
        mx1 = fmaxf(mx1, __shfl_xor(mx1, 32));
        float s0 = 0.f, s1 = 0.f;
        float4 A0 = make_float4(0.f, 0.f, 0.f, 0.f);
        float4 A1 = make_float4(0.f, 0.f, 0.f, 0.f);
        #pragma unroll
        for (int i = 0; i < 13; ++i) {
            float e0 = __expf(z0[i] - mx0);
            float e1 = __expf(z1[i] - mx1);
            s0 += e0; s1 += e1;
            A0.x += e0 * xr[i].x; A0.y += e0 * xr[i].y;
            A0.z += e0 * xr[i].z; A0.w += e0 * xr[i].w;
            A1.x += e1 * xr[i].x; A1.y += e1 * xr[i].y;
            A1.z += e1 * xr[i].z; A1.w += e1 * xr[i].w;
        }
        s0 += __shfl_xor(s0, 32); s1 += __shfl_xor(s1, 32);
        A0.x += __shfl_xor(A0.x, 32); A0.y += __shfl_xor(A0.y, 32);
        A0.z += __shfl_xor(A0.z, 32); A0.w += __shfl_xor(A0.w, 32);
        A1.x += __shfl_xor(A1.x, 32); A1.y += __shfl_xor(A1.y, 32);
        A1.z += __shfl_xor(A1.z, 32); A1.w += __shfl_xor(A1.w, 32);
        const float inv = 1.f / (half ? s1 : s0);
        const float4 S = half ? A1 : A0;
        float4 o;
        o.x = S.x * inv; o.y = S.y * inv; o.z = S.z * inv; o.w = S.w * inv;
        *(float4*)(ws + OFF_Y1 + (size_t)m * 256 + half * 128 + 4 * fl) = o;
    } else if (b < 2816) {
        // ---- attn10: one wave per target
        const int lane = t & 63;
        const int half = lane >> 5;
        const int fl = lane & 31;
        const int m = (b - 2560) * 4 + (t >> 6);
        const float* xnp = h1 + (size_t)m * 1280;
        const float* xsp = h0 + (size_t)m * 128;
        const float4 u0 = *(const float4*)(uv0 + 0 + 4 * fl);
        const float4 u1 = *(const float4*)(uv0 + 128 + 4 * fl);
        const float4 v0 = *(const float4*)(uv0 + 256 + 4 * fl);
        const float4 v1 = *(const float4*)(uv0 + 384 + 4 * fl);

        float4 xr[6];
        xr[0] = *(const float4*)(xsp + 4 * fl);
        #pragma unroll
        for (int i = 1; i < 6; ++i)
            xr[i] = *(const float4*)(xnp + (size_t)(2 * (i - 1) + half) * 128 + 4 * fl);

        float z0[6], z1[6];
        #pragma unroll
        for (int i = 0; i < 6; ++i) {
            float p0 = dot4(xr[i], (i == 0) ? u0 : v0);
            float p1 = dot4(xr[i], (i == 0) ? u1 : v1);
            #pragma unroll
            for (int off = 16; off > 0; off >>= 1) {
                p0 += __shfl_xor(p0, off);
                p1 += __shfl_xor(p1, off);
            }
            z0[i] = p0; z1[i] = p1;
        }
        const float es0 = z0[0];
        const float es1 = z1[0];
        float mx0 = -1e30f, mx1 = -1e30f;
        #pragma unroll
        for (int i = 0; i < 6; ++i) {
            if (i == 0) { z0[i] = -1e30f; z1[i] = -1e30f; }
            else {
                float a = es0 + z0[i]; a = (a >= 0.f) ? a : LRELU_SLOPE * a;
                float c = es1 + z1[i]; c = (c >= 0.f) ? c : LRELU_SLOPE * c;
                z0[i] = a; z1[i] = c;
                mx0 = fmaxf(mx0, a); mx1 = fmaxf(mx1, c);
            }
        }
        mx0 = fmaxf(mx0, __shfl_xor(mx0, 32));
        mx1 = fmaxf(mx1, __shfl_xor(mx1, 32));
        float s0 = 0.f, s1 = 0.f;
        float4 A0 = make_float4(0.f, 0.f, 0.f, 0.f);
        float4 A1 = make_float4(0.f, 0.f, 0.f, 0.f);
        #pragma unroll
        for (int i = 0; i < 6; ++i) {
            float e0 = __expf(z0[i] - mx0);
            float e1 = __expf(z1[i] - mx1);
            s0 += e0; s1 += e1;
            A0.x += e0 * xr[i].x; A0.y += e0 * xr[i].y;
            A0.z += e0 * xr[i].z; A0.w += e0 * xr[i].w;
            A1.x += e1 * xr[i].x; A1.y += e1 * xr[i].y;
            A1.z += e1 * xr[i].z; A1.w += e1 * xr[i].w;
        }
        s0 += __shfl_xor(s0, 32); s1 += __shfl_xor(s1, 32);
        A0.x += __shfl_xor(A0.x, 32); A0.y += __shfl_xor(A0.y, 32);
        A0.z += __shfl_xor(A0.z, 32); A0.w += __shfl_xor(A0.w, 32);
        A1.x += __shfl_xor(A1.x, 32); A1.y += __shfl_xor(A1.y, 32);
        A1.z += __shfl_xor(A1.z, 32); A1.w += __shfl_xor(A1.w, 32);
        const float inv = 1.f / (half ? s1 : s0);
        const float4 S = half ? A1 : A0;
        float4 o;
        o.x = S.x * inv; o.y = S.y * inv; o.z = S.z * inv; o.w = S.w * inv;
        *(float4*)(ws + OFF_Y0 + (size_t)m * 256 + half * 128 + 4 * fl) = o;
    } else if (b < 2944) {
        // ---- P/P' folds
        const int wid = (b - 2816) * 4 + (t >> 6);   // [0,512)
        const int lane = t & 63;
        const int h = wid >> 8, rest = wid & 255;
        const int h0i = rest >> 7;
        const float* wrow = W0 + (size_t)rest * 128;
        float2 w2 = *(const float2*)(wrow + 2 * lane);
        float2 su = *(const float2*)(ws + OFF_U1 + h * 256 + h0i * 128 + 2 * lane);
        float2 sv = *(const float2*)(ws + OFF_V1 + h * 256 + h0i * 128 + 2 * lane);
        float pu = w2.x * su.x + w2.y * su.y;
        float pv = w2.x * sv.x + w2.y * sv.y;
        #pragma unroll
        for (int off = 32; off > 0; off >>= 1) {
            pu += __shfl_xor(pu, off);
            pv += __shfl_xor(pv, off);
        }
        if (lane == 0) { ws[OFF_PP + wid] = pu; ws[OFF_P + wid] = pv; }
    } else {
        // ---- R tiles: R[h][h0*128+f][o] = sum_d W0[h0][f][d] * Q[h][h0*128+d][o]
        __shared__ float smem[4160];
        const int idx = b - 2944;
        const int h = idx >> 3;
        const int h0i = (idx >> 2) & 1;
        const int f0 = (idx & 3) * 32;
        const float* W0h = W0 + (size_t)h0i * 16384;
        for (int ii = t * 4; ii < 32 * 128; ii += 1024) {
            int i = ii >> 7, d = ii & 127;
            float4 g4 = *(const float4*)(W0h + (size_t)(f0 + i) * 128 + d);
            smem[i * 129 + d + 0] = g4.x;
            smem[i * 129 + d + 1] = g4.y;
            smem[i * 129 + d + 2] = g4.z;
            smem[i * 129 + d + 3] = g4.w;
        }
        __syncthreads();
        const int dg = t & 31, rg = t >> 5;
        float4 acc[4];
        #pragma unroll
        for (int j = 0; j < 4; ++j) acc[j] = make_float4(0.f, 0.f, 0.f, 0.f);
        const float* Qp = ws + OFF_Q + (size_t)h * 32768 + (size_t)h0i * 16384 + 4 * dg;
        #pragma unroll 4
        for (int d = 0; d < 128; ++d) {
            float4 q4 = *(const float4*)(Qp + (size_t)d * 128);
            #pragma unroll
            for (int j = 0; j < 4; ++j) {
                float x = smem[(rg * 4 + j) * 129 + d];
                acc[j].x += x * q4.x; acc[j].y += x * q4.y;
                acc[j].z += x * q4.z; acc[j].w += x * q4.w;
            }
        }
        float* Rp = ws + OFF_R + (size_t)h * 32768 + (size_t)h0i * 16384;
        #pragma unroll
        for (int j = 0; j < 4; ++j)
            *(float4*)(Rp + (size_t)(f0 + rg * 4 + j) * 128 + 4 * dg) = acc[j];
    }
}

// ============ FINAL: layer1 attn via P/P' + out = ybar @ R; 2 targets/block ============
// GEMV now reads R ONCE per block: thread halves split the gi-range, each thread
// accumulates BOTH target rows (r=0,1), partials combined in LDS.
__global__ __launch_bounds__(256)
void final_kernel(const float* __restrict__ ws, float* __restrict__ out) {
    __shared__ float xn[22 * 256];
    __shared__ float yb[1024];
    __shared__ float pr[2][2][128];      // [gi-seg][r][o]
    __shared__ float en[2][11][2];
    __shared__ float al[2][10][2];
    const int t = threadIdx.x;
    const int m0 = blockIdx.x * 2;
    const int rlane = t & 63;
    const int rg = t >> 6;
    const float* P  = ws + OFF_P;
    const float* Pp = ws + OFF_PP;
    const float* Y1 = ws + OFF_Y1;
    const float* Y0 = ws + OFF_Y0;
    const float4 su0 = *(const float4*)(Pp + 0 + 4 * rlane);
    const float4 su1 = *(const float4*)(Pp + 256 + 4 * rlane);
    const float4 nv0 = *(const float4*)(P + 0 + 4 * rlane);
    const float4 nv1 = *(const float4*)(P + 256 + 4 * rlane);
    float4 g[6];
    #pragma unroll
    for (int i = 0; i < 6; ++i) {
        int rho = rg + 4 * i;
        if (rho < 22) {
            int r = rho / 11, k = rho % 11;
            int m = m0 + r;
            const float* src = (k < 10) ? (Y1 + ((size_t)m * 10 + k) * 256)
                                        : (Y0 + (size_t)m * 256);
            g[i] = *(const float4*)(src + 4 * rlane);
        }
    }
    #pragma unroll
    for (int i = 0; i < 6; ++i) {
        int rho = rg + 4 * i;
        if (rho < 22) {
            int r = rho / 11, k = rho % 11;
            *(float4*)(&xn[rho * 256 + 4 * rlane]) = g[i];
            float p0 = dot4(g[i], (k < 10) ? nv0 : su0);
            float p1 = dot4(g[i], (k < 10) ? nv1 : su1);
            #pragma unroll
            for (int off = 32; off > 0; off >>= 1) {
                p0 += __shfl_xor(p0, off);
                p1 += __shfl_xor(p1, off);
            }
            if (rlane == 0) { en[r][k][0] = p0; en[r][k][1] = p1; }
        }
    }
    __syncthreads();
    if (t < 128) {
        int r = t >> 6, h = (t >> 5) & 1, k = t & 31;
        float e = -1e30f;
        if (k < 10) {
            float z = en[r][10][h] + en[r][k][h];
            e = (z >= 0.f) ? z : LRELU_SLOPE * z;
        }
        float mx = e;
        #pragma unroll
        for (int off = 16; off > 0; off >>= 1) mx = fmaxf(mx, __shfl_xor(mx, off));
        float ex = (k < 10) ? __expf(e - mx) : 0.f;
        float sm = ex;
        #pragma unroll
        for (int off = 16; off > 0; off >>= 1) sm += __shfl_xor(sm, off);
        if (k < 10) al[r][k][h] = ex / sm;
    }
    __syncthreads();
    #pragma unroll
    for (int i = 0; i < 4; ++i) {
        int c = t + 256 * i;
        int r = c >> 9, rem = c & 511, h = rem >> 8, f = rem & 255;
        float acc = 0.f;
        #pragma unroll
        for (int k = 0; k < 10; ++k) acc += al[r][k][h] * xn[(r * 11 + k) * 256 + f];
        yb[c] = acc;
    }
    __syncthreads();
    // GEMV: out[m0+r][o] = sum_gi yb[r*512+gi] * R[gi][o]
    {
        const int seg = t >> 7;              // gi half: [seg*256, seg*256+256)
        const int o = t & 127;
        const float* Rv = ws + OFF_R + (size_t)seg * 256 * 128 + o;
        const float* y0p = yb + seg * 256;
        const float* y1p = yb + 512 + seg * 256;
        float a0 = 0.f, a1 = 0.f;
        #pragma unroll 8
        for (int gi = 0; gi < 256; ++gi) {
            float rv = Rv[(size_t)gi * 128];
            a0 += y0p[gi] * rv;
            a1 += y1p[gi] * rv;
        }
        pr[seg][0][o] = a0;
        pr[seg][1][o] = a1;
    }
    __syncthreads();
    {
        const int r = t >> 7, o = t & 127;
        out[(size_t)(m0 + r) * 128 + o] = pr[0][r][o] + pr[1][r][o];
    }
}

extern "C" void kernel_launch(void* const* d_in, const int* in_sizes, int n_in,
                              void* d_out, int out_size, void* d_ws, size_t ws_size,
                              hipStream_t stream) {
    const float* h0  = (const float*)d_in[0];
    const float* h1  = (const float*)d_in[1];
    const float* h2  = (const float*)d_in[2];
    const float* W0  = (const float*)d_in[3];
    const float* as0 = (const float*)d_in[4];
    const float* an0 = (const float*)d_in[5];
    const float* W1  = (const float*)d_in[6];
    const float* as1 = (const float*)d_in[7];
    const float* an1 = (const float*)d_in[8];
    const float* fcW = (const float*)d_in[9];
    float* outp = (float*)d_out;
    float* ws = (float*)d_ws;

    hipLaunchKernelGGL(prepA_kernel, dim3(208), dim3(256), 0, stream,
                       W0, as0, an0, W1, as1, an1, fcW, ws);
    hipLaunchKernelGGL(big2_kernel, dim3(2960), dim3(256), 0, stream,
                       h0, h1, h2, W0, ws);
    hipLaunchKernelGGL(final_kernel, dim3(512), dim3(256), 0, stream,
                       ws, outp);
}